// Round 1
// baseline (372.190 us; speedup 1.0000x reference)
//
#include <hip/hip_runtime.h>
#include <stdint.h>

#define T_LEN 8192
#define C_LEN 64
#define OUT_LEN 8

// Kernel A: per row (b,t): pred = argmax_c x[b,t,c] (ties -> lowest c),
// conf = 1 / sum_c exp(x[b,t,c] - max_c) == max of softmax.
// Layout: 16 lanes per row, each lane loads float4 (16 B/lane, 1 KB/wave).
__global__ __launch_bounds__(256) void softmax_stats_kernel(
    const float* __restrict__ x, float* __restrict__ conf,
    int* __restrict__ pred, int nrows)
{
    const int tid  = threadIdx.x;
    const int wave = tid >> 6;
    const int lane = tid & 63;
    const int rw   = lane >> 4;   // row-within-wave (0..3)
    const int sub  = lane & 15;   // 16 lanes per row
    const long long row = (long long)blockIdx.x * 16 + wave * 4 + rw;
    if (row >= nrows) return;

    const float4 v = ((const float4*)(x + row * C_LEN))[sub];

    // local argmax over 4 elems, ties -> lowest index
    float m = v.x; int mi = sub * 4;
    if (v.y > m) { m = v.y; mi = sub * 4 + 1; }
    if (v.z > m) { m = v.z; mi = sub * 4 + 2; }
    if (v.w > m) { m = v.w; mi = sub * 4 + 3; }

    // butterfly over the 16-lane row group (xor masks stay inside the group)
    #pragma unroll
    for (int off = 8; off >= 1; off >>= 1) {
        float om = __shfl_xor(m, off);
        int   oi = __shfl_xor(mi, off);
        if (om > m || (om == m && oi < mi)) { m = om; mi = oi; }
    }

    // sum of exp(x - max): precise expf to track the np reference closely
    float s = expf(v.x - m) + expf(v.y - m) + expf(v.z - m) + expf(v.w - m);
    #pragma unroll
    for (int off = 8; off >= 1; off >>= 1) s += __shfl_xor(s, off);

    if (sub == 0) {
        conf[row] = 1.0f / s;
        pred[row] = mi;
    }
}

// Kernel B: one block per batch sample. RLE + voted-confidence top-8.
__global__ __launch_bounds__(256) void topk_kernel(
    const float* __restrict__ conf, const int* __restrict__ pred,
    float* __restrict__ out)
{
    __shared__ short pred_s[T_LEN];                 // 16 KB
    __shared__ float voted_s[T_LEN];                // 32 KB
    __shared__ unsigned long long wbest[4];

    const int b   = blockIdx.x;
    const int tid = threadIdx.x;
    const int* __restrict__  pb = pred + (long long)b * T_LEN;
    const float* __restrict__ cb = conf + (long long)b * T_LEN;

    for (int t = tid; t < T_LEN; t += 256) pred_s[t] = (short)pb[t];
    __syncthreads();

    // voted confidence at run starts; 0 elsewhere (real voted >= 1/64 > 0)
    for (int t = tid; t < T_LEN; t += 256) {
        const short p = pred_s[t];
        const bool start = (t == 0) || (pred_s[t - 1] != p);
        float v = 0.0f;
        if (start) {
            int len = 1;
            while (t + len < T_LEN && pred_s[t + len] == p) ++len;
            v = cb[t] * (float)len;   // conf at run START times run length
        }
        voted_s[t] = v;
    }
    __syncthreads();

    const int lane = tid & 63, wave = tid >> 6;

    // 8 rounds of block-wide argmax. Key packs (value, ~index):
    // float bits are order-preserving for v >= 0; ~t gives lower-index
    // tie-break exactly like jax.lax.top_k.
    for (int r = 0; r < OUT_LEN; ++r) {
        unsigned long long best = 0ull;
        for (int t = tid; t < T_LEN; t += 256) {
            unsigned long long key =
                ((unsigned long long)__float_as_uint(voted_s[t]) << 32)
                | (unsigned int)(~t);
            if (key > best) best = key;
        }
        #pragma unroll
        for (int off = 32; off >= 1; off >>= 1) {
            unsigned long long o = __shfl_xor(best, off);
            if (o > best) best = o;
        }
        if (lane == 0) wbest[wave] = best;
        __syncthreads();
        if (tid == 0) {
            unsigned long long bb = wbest[0];
            #pragma unroll
            for (int w = 1; w < 4; ++w) if (wbest[w] > bb) bb = wbest[w];
            const unsigned int widx = ~(unsigned int)(bb & 0xffffffffu);
            const float v = __uint_as_float((unsigned int)(bb >> 32));
            float ov = 0.0f;                        // pad-with-0 path
            if (v > 0.0f) { ov = (float)pred_s[widx]; voted_s[widx] = 0.0f; }
            out[b * OUT_LEN + r] = ov;
        }
        __syncthreads();                            // voted_s mutated
    }
}

extern "C" void kernel_launch(void* const* d_in, const int* in_sizes, int n_in,
                              void* d_out, int out_size, void* d_ws, size_t ws_size,
                              hipStream_t stream) {
    const float* x = (const float*)d_in[0];
    const int total = in_sizes[0];          // B*T*C
    const int nrows = total / C_LEN;        // B*T
    const int B     = nrows / T_LEN;

    float* conf = (float*)d_ws;                                   // nrows f32
    int*   pred = (int*)((char*)d_ws + (size_t)nrows * sizeof(float)); // nrows i32
    float* out  = (float*)d_out;

    const int gridA = (nrows + 15) / 16;    // 16 rows per 256-thread block
    softmax_stats_kernel<<<gridA, 256, 0, stream>>>(x, conf, pred, nrows);
    topk_kernel<<<B, 256, 0, stream>>>(conf, pred, out);
}